// Round 2
// baseline (187.949 us; speedup 1.0000x reference)
//
#include <hip/hip_runtime.h>
#include <hip/hip_bf16.h>
#include <math.h>

#define E_N 50
#define D_N 100
#define H_N 100

__device__ __forceinline__ float bf2f(unsigned int s16) {
    return __uint_as_float(s16 << 16);
}

__device__ __forceinline__ unsigned short f2bf(float f) {
    unsigned int u = __float_as_uint(f);
    unsigned int r = (u + 0x7FFFu + ((u >> 16) & 1u)) >> 16;  // round-nearest-even
    return (unsigned short)r;
}

// scalar typed load
template <bool F32>
__device__ __forceinline__ float ldx(const void* p, int i) {
    if (F32) return reinterpret_cast<const float*>(p)[i];
    return bf2f(reinterpret_cast<const unsigned short*>(p)[i]);
}

// 4-element vector load, group index i4 (elements [4*i4, 4*i4+3])
template <bool F32>
__device__ __forceinline__ float4 ld4(const void* p, long long i4) {
    if (F32) return reinterpret_cast<const float4*>(p)[i4];
    uint2 v = reinterpret_cast<const uint2*>(p)[i4];
    float4 f;
    f.x = bf2f(v.x & 0xFFFFu);
    f.y = bf2f(v.x >> 16);
    f.z = bf2f(v.y & 0xFFFFu);
    f.w = bf2f(v.y >> 16);
    return f;
}

// One block per ego-graph. Only node 0's output is needed:
//   s_j   = (u . x_j) * 0.1,  u = Wk * q0,  q0 = Wq^T x0 + bq  (q0.bk cancels)
//   y     = softmax-weighted sum of x_j
//   out_h = bs + bv*[any edge] + y.Wv[:,h] + x0.Ws[:,h]
template <bool F32>
__device__ __forceinline__ void graph_core(
    int g, int tid,
    const int* __restrict__ nbr, const int* __restrict__ adj,
    const void* __restrict__ emb,
    const void* __restrict__ Wq, const void* __restrict__ bq,
    const void* __restrict__ Wk, const void* __restrict__ Wv,
    const void* __restrict__ bv, const void* __restrict__ Ws,
    const void* __restrict__ bs, void* __restrict__ out,
    float* xs, int* ids, int* msk, float* q0s, float* us,
    float* ssc, float* attns, float* ys, float* den_s)
{
    if (tid < E_N) {
        ids[tid] = nbr[g * E_N + tid];
        // mask[g, i=0, j] = adj[g, j, 0]
        msk[tid] = adj[(size_t)g * (E_N * E_N) + tid * E_N];
    }
    __syncthreads();

    // ---- gather emb rows -> xs (f32); 25 groups of 4 elements per row ----
    {
        const int total = E_N * (D_N / 4);  // 1250
        for (int i = tid; i < total; i += 256) {
            int j  = i / 25;
            int d4 = i - j * 25;
            long long base4 = (long long)ids[j] * (D_N / 4) + d4;
            reinterpret_cast<float4*>(xs)[j * 25 + d4] = ld4<F32>(emb, base4);
        }
    }
    __syncthreads();

    // ---- q0[h] = bq[h] + sum_d x0[d] * Wq[d,h] ----
    if (tid < H_N) {
        float acc = ldx<F32>(bq, tid);
        for (int d = 0; d < D_N; ++d)
            acc = fmaf(xs[d], ldx<F32>(Wq, d * H_N + tid), acc);
        q0s[tid] = acc;
    }
    __syncthreads();

    // ---- u[d] = sum_h Wk[d,h] * q0[h] ----
    if (tid < D_N) {
        float acc = 0.f;
        for (int h = 0; h < H_N; ++h)
            acc = fmaf(ldx<F32>(Wk, tid * H_N + h), q0s[h], acc);
        us[tid] = acc;
    }
    __syncthreads();

    // ---- scores s_j = (u . x_j) / sqrt(H) ----
    if (tid < E_N) {
        float acc = 0.f;
        const float* xrow = xs + tid * D_N;
        for (int d = 0; d < D_N; ++d)
            acc = fmaf(us[d], xrow[d], acc);
        ssc[tid] = acc * 0.1f;
    }
    __syncthreads();

    // ---- masked softmax over j (redundant per-thread max) ----
    float m = -3.0e38f;
    for (int j = 0; j < E_N; ++j)
        if (msk[j]) m = fmaxf(m, ssc[j]);
    if (tid < E_N)
        attns[tid] = msk[tid] ? __expf(ssc[tid] - m) : 0.f;
    __syncthreads();

    // ---- y[d] = (sum_j e_j x_j[d]) / den ----
    if (tid < D_N) {
        float den = 0.f;
        for (int j = 0; j < E_N; ++j) den += attns[j];
        float inv = den > 0.f ? 1.0f / den : 0.f;
        float acc = 0.f;
        for (int j = 0; j < E_N; ++j)
            acc = fmaf(attns[j], xs[j * D_N + tid], acc);
        ys[tid] = acc * inv;
        if (tid == 0) *den_s = den;
    }
    __syncthreads();

    // ---- out[h] = bs[h] + bv[h]*[den>0] + y.Wv[:,h] + x0.Ws[:,h] ----
    if (tid < H_N) {
        float sflag = *den_s > 0.f ? 1.f : 0.f;
        float acc = ldx<F32>(bs, tid) + ldx<F32>(bv, tid) * sflag;
        for (int d = 0; d < D_N; ++d) {
            acc = fmaf(ys[d], ldx<F32>(Wv, d * H_N + tid), acc);
            acc = fmaf(xs[d], ldx<F32>(Ws, d * H_N + tid), acc);
        }
        size_t o = (size_t)g * H_N + tid;
        if (F32) reinterpret_cast<float*>(out)[o] = acc;
        else     reinterpret_cast<unsigned short*>(out)[o] = f2bf(acc);
    }
}

__global__ __launch_bounds__(256)
void graph_enc_kernel(const int* __restrict__ nbr,
                      const int* __restrict__ adj,
                      const void* __restrict__ emb,
                      const void* __restrict__ Wq, const void* __restrict__ bq,
                      const void* __restrict__ Wk, const void* __restrict__ Wv,
                      const void* __restrict__ bv, const void* __restrict__ Ws,
                      const void* __restrict__ bs, void* __restrict__ out)
{
    const int g = blockIdx.x;
    const int tid = threadIdx.x;

    __shared__ float xs[E_N * D_N];
    __shared__ int   ids[E_N];
    __shared__ int   msk[E_N];
    __shared__ float q0s[H_N];
    __shared__ float us[D_N];
    __shared__ float ssc[E_N];
    __shared__ float attns[E_N];
    __shared__ float ys[D_N];
    __shared__ float den_s;
    __shared__ int   is_f32_s;

    // ---- dtype detector: even halfwords of emb decode sane iff data is bf16 ----
    if (tid < 64) {
        unsigned short hw = reinterpret_cast<const unsigned short*>(emb)[tid * 2];
        float v = bf2f(hw);
        float a = fabsf(v);
        int sane = (v == 0.f) || (a >= 1e-4f && a <= 8.0f);
        unsigned long long ball = __ballot(sane);
        if (tid == 0) is_f32_s = (__popcll(ball) < 32) ? 1 : 0;
    }
    __syncthreads();

    if (is_f32_s)
        graph_core<true>(g, tid, nbr, adj, emb, Wq, bq, Wk, Wv, bv, Ws, bs, out,
                         xs, ids, msk, q0s, us, ssc, attns, ys, &den_s);
    else
        graph_core<false>(g, tid, nbr, adj, emb, Wq, bq, Wk, Wv, bv, Ws, bs, out,
                          xs, ids, msk, q0s, us, ssc, attns, ys, &den_s);
}

extern "C" void kernel_launch(void* const* d_in, const int* in_sizes, int n_in,
                              void* d_out, int out_size, void* d_ws, size_t ws_size,
                              hipStream_t stream) {
    const int* nbr = (const int*)d_in[0];
    const int* adj = (const int*)d_in[1];
    const void* emb = d_in[2];
    const void* Wq  = d_in[3];
    const void* bq  = d_in[4];
    // d_in[5] = Wk, d_in[6] = bk (bk cancels inside softmax — unused)
    const void* Wk  = d_in[5];
    const void* Wv  = d_in[7];
    const void* bv  = d_in[8];
    const void* Ws  = d_in[9];
    const void* bs  = d_in[10];

    const int G = in_sizes[0] / E_N;  // B*L = 3200
    graph_enc_kernel<<<G, 256, 0, stream>>>(nbr, adj, emb, Wq, bq, Wk,
                                            Wv, bv, Ws, bs, d_out);
}